// Round 10
// baseline (142.830 us; speedup 1.0000x reference)
//
#include <hip/hip_runtime.h>
#include <math.h>

// Problem constants (match reference setup_inputs)
#define B_N   8192      // samples
#define Z_D   128       // feature dim
#define P_N   93        // proxies
#define A_N   2730      // anchors: arange(0, 8189, 3)
#define BCAP  256       // per-anchor suffix-member capacity (max ~180 class)
#define NBLK2 683       // blocks, 4 anchors each (2732 >= 2730)
#define MAGIC 0x5eedf00du
#define TWO_EPS   2e-6f
#define ZEPS2     (128.0f * 1e-6f * 1e-6f)

// Relaxed agent-scope ops: execute at the coherence point, no cache
// maintenance (R5/R6/R9-validated). Distinct-address stores don't contend.
#define AT_LD(p)      __hip_atomic_load((p), __ATOMIC_RELAXED, __HIP_MEMORY_SCOPE_AGENT)
#define AT_ST(p, v)   __hip_atomic_store((p), (v), __ATOMIC_RELAXED, __HIP_MEMORY_SCOPE_AGENT)
#define AT_ADDU(p, v) __hip_atomic_fetch_add((p), (v), __ATOMIC_RELAXED, __HIP_MEMORY_SCOPE_AGENT)

__device__ __forceinline__ float wave_sum(float v) {
#pragma unroll
  for (int off = 1; off < 64; off <<= 1) v += __shfl_xor(v, off, 64);
  return v;
}
__device__ __forceinline__ float wave_min(float v) {
#pragma unroll
  for (int off = 1; off < 64; off <<= 1) v = fminf(v, __shfl_xor(v, off, 64));
  return v;
}

// ONE kernel, NO grid barrier: every block recomputes the cheap shared state
// (proxy norms ~47KB reads) and each wave handles one anchor end-to-end:
// scan y_idx suffix w/ ballot-compaction -> member-row dots -> argmax ->
// logsumexp. Finalize via hierarchical counters (no 683-deep RMW chain).
__global__ __launch_bounds__(256) void kOne(
    const float* __restrict__ z, const int* __restrict__ y_idx,
    const float* __restrict__ prox, float* __restrict__ out,
    float* partial, unsigned int* ctr /*17 x 128B lines*/, unsigned int* flag) {
  __shared__ float lpp[P_N], lsp[P_N], linv[P_N];
  __shared__ int lbkt[4][BCAP];
  __shared__ float lprow[4][Z_D];
  __shared__ float part[4];
  const int b = blockIdx.x, tid = threadIdx.x;
  const int lane = tid & 63, wv = tid >> 6;

  // init control words early (block 0 is in the first dispatch round; all
  // finalize arrivals happen ~10us later). Poison 0xAAAAAAAA != MAGIC.
  if (b == 0 && tid == 0) {
    for (int t = 0; t < 17; ++t) AT_ST(&ctr[t * 32], 0u);
    __builtin_amdgcn_s_waitcnt(0);
    AT_ST(flag, MAGIC);
  }

  // --- preamble: per-block proxy normalization (93 rows, wave round-robin) --
  for (int k = wv; k < P_N; k += 4) {
    const float a = prox[k * Z_D + lane];
    const float c = prox[k * Z_D + 64 + lane];
    const float s = wave_sum(a + c);
    const float q = wave_sum(a * a + c * c);
    const float inv = 1.0f / fmaxf(sqrtf(q), 1e-12f);
    if (lane == 0) {
      lpp[k] = q * inv * inv;   // ||p_hat||^2
      lsp[k] = s * inv;         // sum(p_hat)
      linv[k] = inv;
    }
  }
  __syncthreads();

  // --- per-anchor work: wave wv handles anchor wid ---------------------------
  const int wid = b * 4 + wv;
  float loss = 0.0f;
  if (wid < A_N) {
    const int i = 3 * wid;
    const int ym = y_idx[i];               // y_map is a bijection onto [0,62)
    const int kB = lane + 64;

    // anchor row in registers (coalesced)
    const float zl = z[(size_t)i * Z_D + lane];
    const float zh = z[(size_t)i * Z_D + 64 + lane];
    const float zzi = wave_sum(zl * zl + zh * zh);
    const float szi = wave_sum(zl + zh);

    // step a: distances anchor->all proxies. Per-k wave-reduced dot; lane k
    // (and k-64) keeps its value so the validated per-lane argmin code works.
    float d1 = 0.0f, d2 = 0.0f;
    for (int k = 0; k < P_N; ++k) {
      const float pkl = prox[k * Z_D + lane];
      const float pkh = prox[k * Z_D + 64 + lane];
      const float dt = wave_sum(zl * pkl + zh * pkh) * linv[k];
      d1 = (lane == k) ? dt : d1;
      d2 = (lane == k - 64) ? dt : d2;
    }
    float v1 = fmaxf(zzi + lpp[lane] - 2.0f * d1 +
                     TWO_EPS * (szi - lsp[lane]) + ZEPS2, 0.0f);
    int i1 = lane;
    if (kB < P_N) {
      const float v2 = fmaxf(zzi + lpp[kB] - 2.0f * d2 +
                             TWO_EPS * (szi - lsp[kB]) + ZEPS2, 0.0f);
      if (v2 < v1) { v1 = v2; i1 = kB; }
    }
#pragma unroll
    for (int off = 1; off < 64; off <<= 1) {
      const float ov = __shfl_xor(v1, off, 64);
      const int oi = __shfl_xor(i1, off, 64);
      if (ov < v1 || (ov == v1 && oi < i1)) { v1 = ov; i1 = oi; }
    }
    const int p = i1;                      // wave-uniform

    // stage p_hat_p into this wave's LDS row (broadcast source for members)
    const float ivp = linv[p];
    lprow[wv][lane] = prox[p * Z_D + lane] * ivp;
    lprow[wv][64 + lane] = prox[p * Z_D + 64 + lane] * ivp;

    // scan suffix j>=i for same-class members; ballot-compact into LDS
    int base = 0;
    for (int jb = i & ~63; jb < B_N; jb += 64) {
      const int j = jb + lane;
      const bool m = (j >= i) && (y_idx[j] == ym);
      const unsigned long long mm = __ballot(m);
      if (m) {
        const int pos = base + __popcll(mm & ((1ull << lane) - 1ull));
        if (pos < BCAP) lbkt[wv][pos] = j;
      }
      base += __popcll(mm);
    }
    const int n = min(base, BCAP);         // >= 1 (j=i always matches)

    // step b: parallel member processing; per lane: stream z_j row computing
    // (dot with p_hat_p, sum, sumsq) then running argmax w/ smallest-j ties.
    const float cp = lpp[p] + TWO_EPS * lsp[p] + ZEPS2;
    float best = -INFINITY, q_b = 0.0f, s_b = 0.0f;
    int bestj = 0x7fffffff;
    for (int t = lane; t < ((n + 63) & ~63); t += 64) {
      const bool act = (t < n);
      const int j = act ? lbkt[wv][t] : i; // i is a valid row for idle lanes
      const float* __restrict__ zr = z + (size_t)j * Z_D;
      float dot = 0.0f, s = 0.0f, q = 0.0f;
#pragma unroll 4
      for (int c = 0; c < Z_D; c += 4) {
        const float4 zv = *(const float4*)(zr + c);
        const float4 pv = *(const float4*)(&lprow[wv][c]);  // LDS broadcast
        dot += zv.x * pv.x + zv.y * pv.y + zv.z * pv.z + zv.w * pv.w;
        s += zv.x + zv.y + zv.z + zv.w;
        q += zv.x * zv.x + zv.y * zv.y + zv.z * zv.z + zv.w * zv.w;
      }
      const float w = q - TWO_EPS * s;
      const float vv = fmaxf(cp + w - 2.0f * dot, 0.0f);
      if (act && (vv > best || (vv == best && j < bestj))) {
        best = vv; bestj = j; q_b = q; s_b = s;
      }
    }
#pragma unroll
    for (int off = 1; off < 64; off <<= 1) {
      const float ov = __shfl_xor(best, off, 64);
      const int oj = __shfl_xor(bestj, off, 64);
      const float oq = __shfl_xor(q_b, off, 64);
      const float os = __shfl_xor(s_b, off, 64);
      if (ov > best || (ov == best && oj < bestj)) {
        best = ov; bestj = oj; q_b = oq; s_b = os;
      }
    }
    const float Dp = sqrtf(best);
    const int jp = bestj;
    const float zzj = q_b, szj = s_b;

    // step c: distances jp->all proxies, then logsumexp(-D_n)
    const float yl = z[(size_t)jp * Z_D + lane];
    const float yh = z[(size_t)jp * Z_D + 64 + lane];
    float e1 = 0.0f, e2 = 0.0f;
    for (int k = 0; k < P_N; ++k) {
      const float pkl = prox[k * Z_D + lane];
      const float pkh = prox[k * Z_D + 64 + lane];
      const float dt = wave_sum(yl * pkl + yh * pkh) * linv[k];
      e1 = (lane == k) ? dt : e1;
      e2 = (lane == k - 64) ? dt : e2;
    }
    const float da = sqrtf(fmaxf(zzj + lpp[lane] - 2.0f * e1 +
                                 TWO_EPS * (szj - lsp[lane]) + ZEPS2, 0.0f));
    float db = INFINITY;
    if (kB < P_N)
      db = sqrtf(fmaxf(zzj + lpp[kB] - 2.0f * e2 +
                       TWO_EPS * (szj - lsp[kB]) + ZEPS2, 0.0f));
    const float mn = wave_min(fminf(da, db));
    float ss = expf(mn - da) + ((kB < P_N) ? expf(mn - db) : 0.0f);
    ss = wave_sum(ss);
    loss = Dp - mn + logf(ss);
  }
  if (lane == 0) part[wv] = (wid < A_N) ? loss : 0.0f;
  __syncthreads();

  // --- finalize: waves 1-3 retire now; wave 0 does the hierarchical arrival.
  // partial store is at LLC before the sub RMW; sub-closers' RMWs precede
  // the super RMW; so the last super-arriver sees all 683 partials.
  if (wv == 0) {
    int last = 0;
    if (lane == 0) {
      AT_ST(&partial[b], part[0] + part[1] + part[2] + part[3]);
      __builtin_amdgcn_s_waitcnt(0);       // store completed at LLC
      int g = 0;
      while (AT_LD(flag) != MAGIC) {       // set ~10us ago; instant in practice
        __builtin_amdgcn_s_sleep(2);
        if (++g > (1 << 22)) break;
      }
      const int sub = b & 15;              // 683 = 16*42 + 11
      const unsigned quota = (sub < 11) ? 43u : 42u;
      const unsigned old = AT_ADDU(&ctr[sub * 32], 1u);
      if (old == quota - 1u) {
        const unsigned so = AT_ADDU(&ctr[16 * 32], 1u);
        if (so == 15u) last = 1;
      }
    }
    last = __shfl(last, 0, 64);
    if (last) {                            // one wave reduces 683 partials
      float s = 0.0f;
#pragma unroll
      for (int r = 0; r < 11; ++r) {
        const int t = lane + r * 64;
        if (t < NBLK2) s += AT_LD(&partial[t]);
      }
      s = wave_sum(s);
      if (lane == 0) out[0] = s * (1.0f / (float)A_N);
    }
  }
}

extern "C" void kernel_launch(void* const* d_in, const int* in_sizes, int n_in,
                              void* d_out, int out_size, void* d_ws, size_t ws_size,
                              hipStream_t stream) {
  const float* z = (const float*)d_in[0];      // [8192,128] f32
  const int* y_idx = (const int*)d_in[1];      // [8192] i32
  const float* prox = (const float*)d_in[2];   // [93,128] f32
  // d_in[3] (y_map) is arange(62): y_idx values match it bijectively, so raw
  // y equality substitutes for relative-class equality — not needed on GPU.
  float* out = (float*)d_out;

  // workspace layout (bytes) — ~5.2 KB used
  char* ws = (char*)d_ws;
  unsigned int* ctr  = (unsigned int*)(ws + 0);     // 17 counters, 128B stride
  unsigned int* flag = (unsigned int*)(ws + 2176);  // own line
  float* partial     = (float*)(ws + 2304);         // 683 floats

  kOne<<<NBLK2, 256, 0, stream>>>(z, y_idx, prox, out, partial, ctr, flag);
}

// Round 11
// 90.596 us; speedup vs baseline: 1.5766x; 1.5766x over previous
//
#include <hip/hip_runtime.h>
#include <math.h>

// Problem constants (match reference setup_inputs)
#define B_N   8192      // samples
#define Z_D   128       // feature dim
#define P_N   93        // proxies
#define NCLS  62        // classes
#define A_N   2730      // anchors: arange(0, 8189, 3)
#define BCAP  256       // class-bucket capacity (max expected ~180)
#define GT_S  96        // GT row stride
#define NPART 683       // ceil(A_N / 4) = kB2 grid; 683 = 16*42 + 11
#define TWO_EPS   2e-6f
#define ZEPS2     (128.0f * 1e-6f * 1e-6f)

// Relaxed agent-scope ops: execute at the coherence point, no cache
// maintenance (R5/R6/R9/R10-validated). Distinct-address stores don't
// contend; counter lines see <=43 serialized RMWs (hierarchical finalize).
#define AT_LD(p)      __hip_atomic_load((p), __ATOMIC_RELAXED, __HIP_MEMORY_SCOPE_AGENT)
#define AT_ST(p, v)   __hip_atomic_store((p), (v), __ATOMIC_RELAXED, __HIP_MEMORY_SCOPE_AGENT)
#define AT_ADDU(p, v) __hip_atomic_fetch_add((p), (v), __ATOMIC_RELAXED, __HIP_MEMORY_SCOPE_AGENT)

__device__ __forceinline__ float wave_sum(float v) {
#pragma unroll
  for (int off = 1; off < 64; off <<= 1) v += __shfl_xor(v, off, 64);
  return v;
}
__device__ __forceinline__ float wave_min(float v) {
#pragma unroll
  for (int off = 1; off < 64; off <<= 1) v = fminf(v, __shfl_xor(v, off, 64));
  return v;
}

// --- kA: blocks 0..255 compute GT rows (P1, 1 row/thread, 512 thr); blocks
// 256..317 build class buckets (P0). Kernel boundary = coherent barrier.
// Block 0 zeroes kB2's finalize counters. (Exact R7-benched body.) ----------
__global__ __launch_bounds__(512) void kA(
    const float* __restrict__ z, const int* __restrict__ y_idx,
    const float* __restrict__ prox, const int* __restrict__ y_map,
    float* __restrict__ pp, float* __restrict__ sp,
    float* __restrict__ zz, float* __restrict__ sz,
    int* __restrict__ cnt, int2* __restrict__ bkt, float* __restrict__ GT,
    unsigned int* __restrict__ ctr) {
  __shared__ float linv[6];
  __shared__ int lmem[BCAP];
  __shared__ int lcnt;
  const int b = blockIdx.x, tid = threadIdx.x;
  const int lane = tid & 63, wv = tid >> 6;

  if (b == 0 && tid < 17) ctr[tid * 32] = 0u;  // visible to kB2 via boundary

  if (b < 256) {
    // --- P1: 16 j-chunks x 512 rows (1 row/thread), 16 k-tiles.
    // Tiles 0..14: 6 proxies; tile 15: proxies 90..92 + z row stats.
    const int jch = b & 15, kt = b >> 4, k0 = kt * 6;
    const int nk = (kt == 15) ? 3 : 6;
    const int j = jch * 512 + tid;
    const float* __restrict__ zrow = z + (size_t)j * Z_D;
    if (wv < nk) {                         // per-proxy norm via wave reduce
      const int k = k0 + wv;
      const float a = prox[k * Z_D + lane];
      const float c = prox[k * Z_D + 64 + lane];
      const float s = wave_sum(a + c);
      const float q = wave_sum(a * a + c * c);
      const float inv = 1.0f / fmaxf(sqrtf(q), 1e-12f);
      if (lane == 0) {
        linv[wv] = inv;
        if (jch == 0) { pp[k] = q * inv * inv; sp[k] = s * inv; }
      }
    }
    __syncthreads();
    if (kt < 15) {
      // raw dots vs 6 proxies; proxy addresses are wave-uniform -> s_loads
      const float* __restrict__ p0 = prox + (size_t)(k0 + 0) * Z_D;
      const float* __restrict__ p1 = prox + (size_t)(k0 + 1) * Z_D;
      const float* __restrict__ p2 = prox + (size_t)(k0 + 2) * Z_D;
      const float* __restrict__ p3 = prox + (size_t)(k0 + 3) * Z_D;
      const float* __restrict__ p4 = prox + (size_t)(k0 + 4) * Z_D;
      const float* __restrict__ p5 = prox + (size_t)(k0 + 5) * Z_D;
      float a0 = 0, a1 = 0, a2 = 0, a3 = 0, a4 = 0, a5 = 0;
#pragma unroll 8
      for (int i4 = 0; i4 < Z_D; i4 += 4) {
        const float4 zv = *(const float4*)(zrow + i4);
        const float4 q0 = *(const float4*)(p0 + i4);
        const float4 q1 = *(const float4*)(p1 + i4);
        const float4 q2 = *(const float4*)(p2 + i4);
        const float4 q3 = *(const float4*)(p3 + i4);
        const float4 q4 = *(const float4*)(p4 + i4);
        const float4 q5 = *(const float4*)(p5 + i4);
        a0 += zv.x * q0.x + zv.y * q0.y + zv.z * q0.z + zv.w * q0.w;
        a1 += zv.x * q1.x + zv.y * q1.y + zv.z * q1.z + zv.w * q1.w;
        a2 += zv.x * q2.x + zv.y * q2.y + zv.z * q2.z + zv.w * q2.w;
        a3 += zv.x * q3.x + zv.y * q3.y + zv.z * q3.z + zv.w * q3.w;
        a4 += zv.x * q4.x + zv.y * q4.y + zv.z * q4.z + zv.w * q4.w;
        a5 += zv.x * q5.x + zv.y * q5.y + zv.z * q5.z + zv.w * q5.w;
      }
      const float v0 = linv[0], v1 = linv[1], v2 = linv[2];
      const float v3 = linv[3], v4 = linv[4], v5 = linv[5];
      float* g = GT + (size_t)j * GT_S + k0;       // k0 even -> 8B aligned
      *(float2*)(g + 0) = make_float2(a0 * v0, a1 * v1);
      *(float2*)(g + 2) = make_float2(a2 * v2, a3 * v3);
      *(float2*)(g + 4) = make_float2(a4 * v4, a5 * v5);
    } else {
      const float* __restrict__ p0 = prox + (size_t)90 * Z_D;
      const float* __restrict__ p1 = prox + (size_t)91 * Z_D;
      const float* __restrict__ p2 = prox + (size_t)92 * Z_D;
      float a0 = 0, a1 = 0, a2 = 0, zs = 0, zq = 0;
#pragma unroll 8
      for (int i4 = 0; i4 < Z_D; i4 += 4) {
        const float4 zv = *(const float4*)(zrow + i4);
        const float4 q0 = *(const float4*)(p0 + i4);
        const float4 q1 = *(const float4*)(p1 + i4);
        const float4 q2 = *(const float4*)(p2 + i4);
        zs += zv.x + zv.y + zv.z + zv.w;
        zq += zv.x * zv.x + zv.y * zv.y + zv.z * zv.z + zv.w * zv.w;
        a0 += zv.x * q0.x + zv.y * q0.y + zv.z * q0.z + zv.w * q0.w;
        a1 += zv.x * q1.x + zv.y * q1.y + zv.z * q1.z + zv.w * q1.w;
        a2 += zv.x * q2.x + zv.y * q2.y + zv.z * q2.z + zv.w * q2.w;
      }
      float* g = GT + (size_t)j * GT_S + 90;       // 90 even -> 8B aligned
      *(float2*)(g) = make_float2(a0 * linv[0], a1 * linv[1]);
      g[2] = a2 * linv[2];
      zz[j] = zq;
      sz[j] = zs;
    }
  } else {
    // --- P0: class c = b-256 claims its samples (y_map unique), packs
    // (j, w_j = zz_j - 2*eps*sz_j) into bucket entries. LDS atomics only.
    const int c = b - 256;
    if (tid == 0) lcnt = 0;
    __syncthreads();
    const int ym = y_map[c];
    for (int j = tid; j < B_N; j += 512) {
      if (y_idx[j] == ym) {
        const int pos = atomicAdd(&lcnt, 1);
        if (pos < BCAP) lmem[pos] = j;
      }
    }
    __syncthreads();
    const int n = min(lcnt, BCAP);
    if (tid == 0) cnt[c] = n;
    for (int m = wv; m < n; m += 8) {      // one member per wave, round-robin
      const int j = lmem[m];
      const float a = z[(size_t)j * Z_D + lane];
      const float c2 = z[(size_t)j * Z_D + 64 + lane];
      const float s = wave_sum(a + c2);
      const float q = wave_sum(a * a + c2 * c2);
      if (lane == 0)
        bkt[c * BCAP + m] = make_int2(j, __float_as_int(q - TWO_EPS * s));
    }
  }
}

// --- kB2: one wave per anchor (exact R7-benched body); finalize via R10's
// validated hierarchical counters — no 683-deep RMW chain, no extra node. ---
__global__ __launch_bounds__(256) void kB2(
    const int* __restrict__ y_idx, const int* __restrict__ y_map,
    const float* __restrict__ pp, const float* __restrict__ sp,
    const float* __restrict__ zz, const float* __restrict__ sz,
    const int* __restrict__ cnt, const int2* __restrict__ bkt,
    const float* __restrict__ GT, float* partial, unsigned int* ctr,
    float* __restrict__ out) {
  __shared__ float lpp[P_N], lsp[P_N];
  __shared__ int lymap[NCLS];
  __shared__ float part[4];
  const int b = blockIdx.x;
  const int tid = threadIdx.x, lane = tid & 63, wv = tid >> 6;
  if (tid < P_N) { lpp[tid] = pp[tid]; lsp[tid] = sp[tid]; }
  if (tid < NCLS) lymap[tid] = y_map[tid];
  __syncthreads();

  const int wid = b * 4 + wv;
  float loss = 0.0f;
  if (wid < A_N) {
    const int i = 3 * wid;
    const int yi = y_idx[i];
    const unsigned long long mm = __ballot(lane < NCLS && lymap[lane] == yi);
    const int cls = __ffsll(mm) - 1;       // unique match (y_map unique)
    const float zzi = zz[i], szi = sz[i];
    const int kB = lane + 64;

    // step a: nearest proxy (argmin, first-index tie-break)
    const float* __restrict__ GTi = GT + (size_t)i * GT_S;
    float v1 = fmaxf(zzi + lpp[lane] - 2.0f * GTi[lane] +
                     TWO_EPS * (szi - lsp[lane]) + ZEPS2, 0.0f);
    int i1 = lane;
    if (kB < P_N) {
      const float v2 = fmaxf(zzi + lpp[kB] - 2.0f * GTi[kB] +
                             TWO_EPS * (szi - lsp[kB]) + ZEPS2, 0.0f);
      if (v2 < v1) { v1 = v2; i1 = kB; }
    }
#pragma unroll
    for (int off = 1; off < 64; off <<= 1) {
      const float ov = __shfl_xor(v1, off, 64);
      const int oi = __shfl_xor(i1, off, 64);
      if (ov < v1 || (ov == v1 && oi < i1)) { v1 = ov; i1 = oi; }
    }
    const int p = i1;

    // step b: hardest positive in same-class suffix; bucket entry carries
    // (j, w_j) in one 8B load -> single dependent gather on GT.
    const float cp = lpp[p] + TWO_EPS * lsp[p] + ZEPS2;
    const int n = cnt[cls];
    const int2* __restrict__ bk = bkt + cls * BCAP;
    float best = -INFINITY;
    int bestj = 0x7fffffff;
    for (int t = lane; t < n; t += 64) {
      const int2 e = bk[t];
      const int jj = e.x;
      if (jj >= i) {
        const float vv = fmaxf(cp + __int_as_float(e.y) -
                               2.0f * GT[(size_t)jj * GT_S + p], 0.0f);
        if (vv > best || (vv == best && jj < bestj)) { best = vv; bestj = jj; }
      }
    }
#pragma unroll
    for (int off = 1; off < 64; off <<= 1) {
      const float ov = __shfl_xor(best, off, 64);
      const int oj = __shfl_xor(bestj, off, 64);
      if (ov > best || (ov == best && oj < bestj)) { best = ov; bestj = oj; }
    }
    const float Dp = sqrtf(best);
    const int jp = bestj;

    // step c: logsumexp(-D_n) over proxies
    const float zzj = zz[jp], szj = sz[jp];
    const float* __restrict__ GTj = GT + (size_t)jp * GT_S;
    const float d1 = sqrtf(fmaxf(zzj + lpp[lane] - 2.0f * GTj[lane] +
                                 TWO_EPS * (szj - lsp[lane]) + ZEPS2, 0.0f));
    float d2 = INFINITY;
    if (kB < P_N)
      d2 = sqrtf(fmaxf(zzj + lpp[kB] - 2.0f * GTj[kB] +
                       TWO_EPS * (szj - lsp[kB]) + ZEPS2, 0.0f));
    const float mn = wave_min(fminf(d1, d2));
    float ss = expf(mn - d1) + ((kB < P_N) ? expf(mn - d2) : 0.0f);
    ss = wave_sum(ss);
    loss = Dp - mn + logf(ss);
  }
  if (lane == 0) part[wv] = (wid < A_N) ? loss : 0.0f;
  __syncthreads();

  // finalize (R10-validated): distinct-address partial store -> drain ->
  // sub-counter RMW (<=43 deep); sub closer bumps super; last block's wave 0
  // reduces all 683 partials. Waves 1-3 retire immediately.
  if (wv == 0) {
    int last = 0;
    if (lane == 0) {
      AT_ST(&partial[b], part[0] + part[1] + part[2] + part[3]);
      __builtin_amdgcn_s_waitcnt(0);       // store completed at LLC
      const int sub = b & 15;              // residues 0..10: 43 blocks; 11..15: 42
      const unsigned quota = (sub < 11) ? 43u : 42u;
      const unsigned old = AT_ADDU(&ctr[sub * 32], 1u);
      if (old == quota - 1u) {             // RMW result dependency orders this
        const unsigned so = AT_ADDU(&ctr[16 * 32], 1u);
        if (so == 15u) last = 1;
      }
    }
    last = __shfl(last, 0, 64);
    if (last) {                            // one wave reduces 683 partials
      float s = 0.0f;
#pragma unroll
      for (int r = 0; r < 11; ++r) {
        const int t = lane + r * 64;
        if (t < NPART) s += AT_LD(&partial[t]);
      }
      s = wave_sum(s);
      if (lane == 0) out[0] = s * (1.0f / (float)A_N);
    }
  }
}

extern "C" void kernel_launch(void* const* d_in, const int* in_sizes, int n_in,
                              void* d_out, int out_size, void* d_ws, size_t ws_size,
                              hipStream_t stream) {
  const float* z = (const float*)d_in[0];      // [8192,128] f32
  const int* y_idx = (const int*)d_in[1];      // [8192] i32
  const float* prox = (const float*)d_in[2];   // [93,128] f32
  const int* y_map = (const int*)d_in[3];      // [62] i32
  float* out = (float*)d_out;

  // workspace layout (bytes), ~3.35 MB
  char* ws = (char*)d_ws;
  unsigned int* ctr = (unsigned int*)(ws + 0); // 17 counters, 128B stride
  float* pp    = (float*)(ws + 2560);          // 93*4 (pad 512)
  float* sp    = (float*)(ws + 3072);          // 93*4 (pad 512) -> 3584
  float* zz    = (float*)(ws + 3584);          // 8192*4 -> 36352
  float* sz    = (float*)(ws + 36352);         // -> 69120
  int*   cnt   = (int*)  (ws + 69120);         // 62*4 (pad 256) -> 69376
  int2*  bkt   = (int2*) (ws + 69376);         // 62*256*8 -> 196352
  float* parts = (float*)(ws + 196352);        // 683*4 (pad) -> 199168
  float* GT    = (float*)(ws + 199168);        // 8192*96*4 -> 3344896

  kA<<<256 + NCLS, 512, 0, stream>>>(z, y_idx, prox, y_map,
                                     pp, sp, zz, sz, cnt, bkt, GT, ctr);
  kB2<<<NPART, 256, 0, stream>>>(y_idx, y_map, pp, sp, zz, sz,
                                 cnt, bkt, GT, parts, ctr, out);
}

// Round 12
// 81.439 us; speedup vs baseline: 1.7538x; 1.1124x over previous
//
#include <hip/hip_runtime.h>
#include <math.h>

// Problem constants (match reference setup_inputs)
#define B_N   8192      // samples
#define Z_D   128       // feature dim
#define P_N   93        // proxies
#define NCLS  62        // classes
#define A_N   2730      // anchors: arange(0, 8189, 3)
#define BCAP  256       // class-bucket capacity (max expected ~180)
#define GT_S  96        // GT row stride
#define NPART 683       // ceil(A_N / 4) = kB2 grid; 683 = 16*42 + 11
#define TWO_EPS   2e-6f
#define ZEPS2     (128.0f * 1e-6f * 1e-6f)

// Relaxed agent-scope ops: coherence-point execution, no cache maintenance
// (R5/R6/R10/R11-validated). Hierarchical counters keep RMW chains <=43 deep.
#define AT_LD(p)      __hip_atomic_load((p), __ATOMIC_RELAXED, __HIP_MEMORY_SCOPE_AGENT)
#define AT_ST(p, v)   __hip_atomic_store((p), (v), __ATOMIC_RELAXED, __HIP_MEMORY_SCOPE_AGENT)
#define AT_ADDU(p, v) __hip_atomic_fetch_add((p), (v), __ATOMIC_RELAXED, __HIP_MEMORY_SCOPE_AGENT)

__device__ __forceinline__ float wave_sum(float v) {
#pragma unroll
  for (int off = 1; off < 64; off <<= 1) v += __shfl_xor(v, off, 64);
  return v;
}
__device__ __forceinline__ float wave_min(float v) {
#pragma unroll
  for (int off = 1; off < 64; off <<= 1) v = fminf(v, __shfl_xor(v, off, 64));
  return v;
}

// --- kA: blocks 0..255 compute GT rows (P1, LDS-staged pre-scaled proxy
// tile, 1 row/thread); blocks 256..317 compact class index buckets (P0, no
// member reductions — w[] comes from P1 tile 15). Kernel boundary = barrier.
__global__ __launch_bounds__(512) void kA(
    const float* __restrict__ z, const int* __restrict__ y_idx,
    const float* __restrict__ prox, const int* __restrict__ y_map,
    float* __restrict__ pp, float* __restrict__ sp,
    float* __restrict__ zz, float* __restrict__ sz, float* __restrict__ w,
    int* __restrict__ cnt, int* __restrict__ bkt, float* __restrict__ GT,
    unsigned int* __restrict__ ctr) {
  __shared__ float linv[6];
  __shared__ float pt[6 * Z_D];            // pre-scaled proxy tile (3 KB)
  __shared__ int lcnt;
  const int b = blockIdx.x, tid = threadIdx.x;
  const int lane = tid & 63, wv = tid >> 6;

  if (b == 0 && tid < 17) ctr[tid * 32] = 0u;  // visible to kB2 via boundary

  if (b < 256) {
    // --- P1: 16 j-chunks x 512 rows (1 row/thread), 16 k-tiles.
    // Tiles 0..14: 6 proxies; tile 15: proxies 90..92 + z row stats + w.
    const int jch = b & 15, kt = b >> 4, k0 = kt * 6;
    const int nk = (kt == 15) ? 3 : 6;
    const int j = jch * 512 + tid;
    const float* __restrict__ zrow = z + (size_t)j * Z_D;
    if (wv < nk) {                         // per-proxy norm via wave reduce
      const int k = k0 + wv;
      const float a = prox[k * Z_D + lane];
      const float c = prox[k * Z_D + 64 + lane];
      const float s = wave_sum(a + c);
      const float q = wave_sum(a * a + c * c);
      const float inv = 1.0f / fmaxf(sqrtf(q), 1e-12f);
      if (lane == 0) {
        linv[wv] = inv;
        if (jch == 0) { pp[k] = q * inv * inv; sp[k] = s * inv; }
      }
    }
    __syncthreads();
    // stage tile into LDS, pre-scaled by inv-norm (t>>5 = row, 32 f4/row)
    {
      const int nf = nk * 32;
      const float4* __restrict__ src = (const float4*)(prox + (size_t)k0 * Z_D);
      for (int t = tid; t < nf; t += 512) {
        const float iv = linv[t >> 5];
        const float4 v = src[t];
        ((float4*)pt)[t] = make_float4(v.x * iv, v.y * iv, v.z * iv, v.w * iv);
      }
    }
    __syncthreads();
    if (kt < 15) {
      float a0 = 0, a1 = 0, a2 = 0, a3 = 0, a4 = 0, a5 = 0;
#pragma unroll 8
      for (int i4 = 0; i4 < Z_D; i4 += 4) {
        const float4 zv = *(const float4*)(zrow + i4);
        const int f = i4 >> 2;
        const float4 q0 = ((const float4*)pt)[0 * 32 + f];  // LDS broadcast
        const float4 q1 = ((const float4*)pt)[1 * 32 + f];
        const float4 q2 = ((const float4*)pt)[2 * 32 + f];
        const float4 q3 = ((const float4*)pt)[3 * 32 + f];
        const float4 q4 = ((const float4*)pt)[4 * 32 + f];
        const float4 q5 = ((const float4*)pt)[5 * 32 + f];
        a0 += zv.x * q0.x + zv.y * q0.y + zv.z * q0.z + zv.w * q0.w;
        a1 += zv.x * q1.x + zv.y * q1.y + zv.z * q1.z + zv.w * q1.w;
        a2 += zv.x * q2.x + zv.y * q2.y + zv.z * q2.z + zv.w * q2.w;
        a3 += zv.x * q3.x + zv.y * q3.y + zv.z * q3.z + zv.w * q3.w;
        a4 += zv.x * q4.x + zv.y * q4.y + zv.z * q4.z + zv.w * q4.w;
        a5 += zv.x * q5.x + zv.y * q5.y + zv.z * q5.z + zv.w * q5.w;
      }
      float* g = GT + (size_t)j * GT_S + k0;       // k0 even -> 8B aligned
      *(float2*)(g + 0) = make_float2(a0, a1);
      *(float2*)(g + 2) = make_float2(a2, a3);
      *(float2*)(g + 4) = make_float2(a4, a5);
    } else {
      float a0 = 0, a1 = 0, a2 = 0, zs = 0, zq = 0;
#pragma unroll 8
      for (int i4 = 0; i4 < Z_D; i4 += 4) {
        const float4 zv = *(const float4*)(zrow + i4);
        const int f = i4 >> 2;
        const float4 q0 = ((const float4*)pt)[0 * 32 + f];
        const float4 q1 = ((const float4*)pt)[1 * 32 + f];
        const float4 q2 = ((const float4*)pt)[2 * 32 + f];
        zs += zv.x + zv.y + zv.z + zv.w;
        zq += zv.x * zv.x + zv.y * zv.y + zv.z * zv.z + zv.w * zv.w;
        a0 += zv.x * q0.x + zv.y * q0.y + zv.z * q0.z + zv.w * q0.w;
        a1 += zv.x * q1.x + zv.y * q1.y + zv.z * q1.z + zv.w * q1.w;
        a2 += zv.x * q2.x + zv.y * q2.y + zv.z * q2.z + zv.w * q2.w;
      }
      float* g = GT + (size_t)j * GT_S + 90;       // 90 even -> 8B aligned
      *(float2*)(g) = make_float2(a0, a1);
      g[2] = a2;
      zz[j] = zq;
      sz[j] = zs;
      w[j] = zq - TWO_EPS * zs;            // per-j part of pdist(prox, z)
    }
  } else {
    // --- P0: class c = b-256 compacts its sample indices (y_map unique).
    // No per-member math — kB2 gathers w[jj] (computed by P1 tile 15).
    const int c = b - 256;
    if (tid == 0) lcnt = 0;
    __syncthreads();
    const int ym = y_map[c];
    for (int j = tid; j < B_N; j += 512) {
      if (y_idx[j] == ym) {
        const int pos = atomicAdd(&lcnt, 1);     // LDS atomic
        if (pos < BCAP) bkt[c * BCAP + pos] = j;
      }
    }
    __syncthreads();
    if (tid == 0) cnt[c] = min(lcnt, BCAP);
  }
}

// --- kB2: one wave per anchor (R6-validated step-b w-gather shape);
// R10/R11-validated hierarchical finalize. ----------------------------------
__global__ __launch_bounds__(256) void kB2(
    const int* __restrict__ y_idx, const int* __restrict__ y_map,
    const float* __restrict__ pp, const float* __restrict__ sp,
    const float* __restrict__ zz, const float* __restrict__ sz,
    const float* __restrict__ w,
    const int* __restrict__ cnt, const int* __restrict__ bkt,
    const float* __restrict__ GT, float* partial, unsigned int* ctr,
    float* __restrict__ out) {
  __shared__ float lpp[P_N], lsp[P_N];
  __shared__ int lymap[NCLS];
  __shared__ float part[4];
  const int b = blockIdx.x;
  const int tid = threadIdx.x, lane = tid & 63, wv = tid >> 6;
  if (tid < P_N) { lpp[tid] = pp[tid]; lsp[tid] = sp[tid]; }
  if (tid < NCLS) lymap[tid] = y_map[tid];
  __syncthreads();

  const int wid = b * 4 + wv;
  float loss = 0.0f;
  if (wid < A_N) {
    const int i = 3 * wid;
    const int yi = y_idx[i];
    const unsigned long long mm = __ballot(lane < NCLS && lymap[lane] == yi);
    const int cls = __ffsll(mm) - 1;       // unique match (y_map unique)
    const float zzi = zz[i], szi = sz[i];
    const int kB = lane + 64;

    // step a: nearest proxy (argmin, first-index tie-break)
    const float* __restrict__ GTi = GT + (size_t)i * GT_S;
    float v1 = fmaxf(zzi + lpp[lane] - 2.0f * GTi[lane] +
                     TWO_EPS * (szi - lsp[lane]) + ZEPS2, 0.0f);
    int i1 = lane;
    if (kB < P_N) {
      const float v2 = fmaxf(zzi + lpp[kB] - 2.0f * GTi[kB] +
                             TWO_EPS * (szi - lsp[kB]) + ZEPS2, 0.0f);
      if (v2 < v1) { v1 = v2; i1 = kB; }
    }
#pragma unroll
    for (int off = 1; off < 64; off <<= 1) {
      const float ov = __shfl_xor(v1, off, 64);
      const int oi = __shfl_xor(i1, off, 64);
      if (ov < v1 || (ov == v1 && oi < i1)) { v1 = ov; i1 = oi; }
    }
    const int p = i1;

    // step b: hardest positive in same-class suffix (w-gather, R6 shape)
    const float cp = lpp[p] + TWO_EPS * lsp[p] + ZEPS2;
    const int n = cnt[cls];
    const int* __restrict__ bk = bkt + cls * BCAP;
    float best = -INFINITY;
    int bestj = 0x7fffffff;
    for (int t = lane; t < n; t += 64) {
      const int jj = bk[t];
      if (jj >= i) {
        const float vv = fmaxf(cp + w[jj] - 2.0f * GT[(size_t)jj * GT_S + p], 0.0f);
        if (vv > best || (vv == best && jj < bestj)) { best = vv; bestj = jj; }
      }
    }
#pragma unroll
    for (int off = 1; off < 64; off <<= 1) {
      const float ov = __shfl_xor(best, off, 64);
      const int oj = __shfl_xor(bestj, off, 64);
      if (ov > best || (ov == best && oj < bestj)) { best = ov; bestj = oj; }
    }
    const float Dp = sqrtf(best);
    const int jp = bestj;

    // step c: logsumexp(-D_n) over proxies
    const float zzj = zz[jp], szj = sz[jp];
    const float* __restrict__ GTj = GT + (size_t)jp * GT_S;
    const float d1 = sqrtf(fmaxf(zzj + lpp[lane] - 2.0f * GTj[lane] +
                                 TWO_EPS * (szj - lsp[lane]) + ZEPS2, 0.0f));
    float d2 = INFINITY;
    if (kB < P_N)
      d2 = sqrtf(fmaxf(zzj + lpp[kB] - 2.0f * GTj[kB] +
                       TWO_EPS * (szj - lsp[kB]) + ZEPS2, 0.0f));
    const float mn = wave_min(fminf(d1, d2));
    float ss = expf(mn - d1) + ((kB < P_N) ? expf(mn - d2) : 0.0f);
    ss = wave_sum(ss);
    loss = Dp - mn + logf(ss);
  }
  if (lane == 0) part[wv] = (wid < A_N) ? loss : 0.0f;
  __syncthreads();

  // finalize (R10/R11-validated): distinct-address partial store -> drain ->
  // sub-counter RMW (<=43 deep); sub closer bumps super; last block's wave 0
  // reduces all 683 partials. Waves 1-3 retire immediately.
  if (wv == 0) {
    int last = 0;
    if (lane == 0) {
      AT_ST(&partial[b], part[0] + part[1] + part[2] + part[3]);
      __builtin_amdgcn_s_waitcnt(0);       // store completed at LLC
      const int sub = b & 15;              // residues 0..10: 43; 11..15: 42
      const unsigned quota = (sub < 11) ? 43u : 42u;
      const unsigned old = AT_ADDU(&ctr[sub * 32], 1u);
      if (old == quota - 1u) {
        const unsigned so = AT_ADDU(&ctr[16 * 32], 1u);
        if (so == 15u) last = 1;
      }
    }
    last = __shfl(last, 0, 64);
    if (last) {                            // one wave reduces 683 partials
      float s = 0.0f;
#pragma unroll
      for (int r = 0; r < 11; ++r) {
        const int t = lane + r * 64;
        if (t < NPART) s += AT_LD(&partial[t]);
      }
      s = wave_sum(s);
      if (lane == 0) out[0] = s * (1.0f / (float)A_N);
    }
  }
}

extern "C" void kernel_launch(void* const* d_in, const int* in_sizes, int n_in,
                              void* d_out, int out_size, void* d_ws, size_t ws_size,
                              hipStream_t stream) {
  const float* z = (const float*)d_in[0];      // [8192,128] f32
  const int* y_idx = (const int*)d_in[1];      // [8192] i32
  const float* prox = (const float*)d_in[2];   // [93,128] f32
  const int* y_map = (const int*)d_in[3];      // [62] i32
  float* out = (float*)d_out;

  // workspace layout (bytes), ~3.31 MB
  char* ws = (char*)d_ws;
  unsigned int* ctr = (unsigned int*)(ws + 0); // 17 counters, 128B stride
  float* pp    = (float*)(ws + 2560);          // 93*4 (pad 512)
  float* sp    = (float*)(ws + 3072);          // 93*4 (pad 512) -> 3584
  float* zz    = (float*)(ws + 3584);          // 8192*4 -> 36352
  float* sz    = (float*)(ws + 36352);         // -> 69120
  float* w     = (float*)(ws + 69120);         // -> 101888
  int*   cnt   = (int*)  (ws + 101888);        // 62*4 (pad 256) -> 102144
  int*   bkt   = (int*)  (ws + 102144);        // 62*256*4 -> 165632
  float* parts = (float*)(ws + 165632);        // 683*4 (pad) -> 168448
  float* GT    = (float*)(ws + 168448);        // 8192*96*4 -> 3314176

  kA<<<256 + NCLS, 512, 0, stream>>>(z, y_idx, prox, y_map,
                                     pp, sp, zz, sz, w, cnt, bkt, GT, ctr);
  kB2<<<NPART, 256, 0, stream>>>(y_idx, y_map, pp, sp, zz, sz, w,
                                 cnt, bkt, GT, parts, ctr, out);
}